// Round 15
// baseline (167.904 us; speedup 1.0000x reference)
//
#include <hip/hip_runtime.h>
#include <stdint.h>

// Problem constants
#define DIMC   256
#define NHEADS 8
#define HD     32
#define BATCH  4
#define SEQ    2048
#define MTOT   (BATCH * SEQ)        // 8192 tokens
#define QKVN   (MTOT * HD * NHEADS) // 2097152 elements per q/k/v tensor
#define SCALE  0.17677669529663687f // 1/sqrt(32)
#define LOG2E  1.4426950408889634f
#define SCL2E  (SCALE * LOG2E)

typedef short bf16x8 __attribute__((ext_vector_type(8)));
typedef float f32x4  __attribute__((ext_vector_type(4)));

#if defined(__has_builtin)
#if __has_builtin(__builtin_amdgcn_exp2f)
#define EXP2F __builtin_amdgcn_exp2f
#else
#define EXP2F exp2f
#endif
#else
#define EXP2F exp2f
#endif

static __device__ __forceinline__ unsigned short f2bf(float f) {
    unsigned int u = __float_as_uint(f);
    u += 0x7fffu + ((u >> 16) & 1u);   // RNE
    return (unsigned short)(u >> 16);
}

static __device__ __forceinline__ unsigned int cvt2(float a, float b) {
#if defined(__has_builtin) && __has_builtin(__builtin_amdgcn_cvt_pk_bf16_f32)
    typedef __bf16 bf2 __attribute__((ext_vector_type(2)));
    bf2 v = __builtin_amdgcn_cvt_pk_bf16_f32(a, b);
    return __builtin_bit_cast(unsigned int, v);
#else
    return (unsigned int)f2bf(a) | ((unsigned int)f2bf(b) << 16);
#endif
}

// load 8 consecutive fp32 and pack to a bf16x8 fragment
static __device__ __forceinline__ bf16x8 ld8f_bf(const float* p) {
    float4 a0 = *(const float4*)p;
    float4 a1 = *(const float4*)(p + 4);
    uint4 pk;
    pk.x = cvt2(a0.x, a0.y); pk.y = cvt2(a0.z, a0.w);
    pk.z = cvt2(a1.x, a1.y); pk.w = cvt2(a1.z, a1.w);
    return __builtin_bit_cast(bf16x8, pk);
}

// ---------------------------------------------------------------------------
// QKV GEMM, BARRIER-FREE: no LDS, no __syncthreads. Each wave owns a 16-col
// n-slice; its full-K W slice lives in registers (8 x bf16x8 = 32 VGPRs).
// A-fragments stream from global fp32 (L1-hot across the block's 4 waves).
// Block = 128 m x 64 n; grid (12 n-tiles, 64 m-groups).
// q pre-scaled by SCALE*log2e; V stored transposed [bh][hd][seq] with packed
// b64 stores (4 consecutive seq per store; wave covers full 64B lines).
// ---------------------------------------------------------------------------
__global__ __launch_bounds__(256) void gemm_qkv_kernel(
    const float* __restrict__ A,
    const float* __restrict__ W,
    const float* __restrict__ bias,
    unsigned short* __restrict__ qb,
    unsigned short* __restrict__ kb,
    unsigned short* __restrict__ vtb)
{
    const int t    = threadIdx.x;
    const int wave = t >> 6;
    const int lane = t & 63;
    const int cg   = lane & 15;
    const int quad = lane >> 4;
    const int n0   = blockIdx.x * 64;
    const int mg   = blockIdx.y * 128;

    const int n = n0 + wave * 16 + cg;      // this lane's output column
    // W slice for column n, all K, in registers
    bf16x8 wf[8];
    #pragma unroll
    for (int chunk = 0; chunk < 8; chunk++)
        wf[chunk] = ld8f_bf(W + (size_t)n * 256 + chunk * 32 + quad * 8);

    const int which = n >> 8;               // 0 q, 1 k, 2 v
    const int h     = (n >> 5) & 7;
    const int d     = n & 31;
    const float bv  = bias[n];

    #pragma unroll
    for (int l = 0; l < 2; l++) {
        const int m0l = mg + l * 64;
        const float* Ab = A + (size_t)m0l * 256;

        f32x4 acc[4];
        #pragma unroll
        for (int mi = 0; mi < 4; mi++) acc[mi] = (f32x4){0.f, 0.f, 0.f, 0.f};

        #pragma unroll
        for (int chunk = 0; chunk < 8; chunk++) {
            #pragma unroll
            for (int mi = 0; mi < 4; mi++) {
                bf16x8 af = ld8f_bf(Ab + (size_t)(mi * 16 + cg) * 256 + chunk * 32 + quad * 8);
                acc[mi] = __builtin_amdgcn_mfma_f32_16x16x32_bf16(af, wf[chunk], acc[mi], 0, 0, 0);
            }
        }

        const int b_ = m0l >> 11;
        const int bh = b_ * NHEADS + h;
        if (which == 0) {
            #pragma unroll
            for (int mi = 0; mi < 4; mi++)
                #pragma unroll
                for (int rr = 0; rr < 4; rr++) {
                    int nn = (m0l & 2047) + mi * 16 + quad * 4 + rr;
                    qb[((size_t)bh * SEQ + nn) * HD + d] = f2bf((acc[mi][rr] + bv) * SCL2E);
                }
        } else if (which == 1) {
            #pragma unroll
            for (int mi = 0; mi < 4; mi++)
                #pragma unroll
                for (int rr = 0; rr < 4; rr++) {
                    int nn = (m0l & 2047) + mi * 16 + quad * 4 + rr;
                    kb[((size_t)bh * SEQ + nn) * HD + d] = f2bf(acc[mi][rr] + bv);
                }
        } else {
            // Vt[bh][d][seq]: pack 4 consecutive seq (quad*4+rr) into one b64
            unsigned short* vrow = vtb + ((size_t)bh * HD + d) * SEQ;
            #pragma unroll
            for (int mi = 0; mi < 4; mi++) {
                int nn = (m0l & 2047) + mi * 16 + quad * 4;
                uint2 pk;
                pk.x = cvt2(acc[mi][0] + bv, acc[mi][1] + bv);
                pk.y = cvt2(acc[mi][2] + bv, acc[mi][3] + bv);
                *(uint2*)(vrow + nn) = pk;
            }
        }
    }
}

// ---------------------------------------------------------------------------
// Projection GEMM, BARRIER-FREE (same structure). A = bf16 ao; W fp32 ->
// register-resident bf16 slice; fp32 scatter store. Grid (4, 64).
// ---------------------------------------------------------------------------
__global__ __launch_bounds__(256) void gemm_proj_kernel(
    const unsigned short* __restrict__ A,
    const float* __restrict__ W,
    const float* __restrict__ bias,
    float* __restrict__ outf)
{
    const int t    = threadIdx.x;
    const int wave = t >> 6;
    const int lane = t & 63;
    const int cg   = lane & 15;
    const int quad = lane >> 4;
    const int n0   = blockIdx.x * 64;
    const int mg   = blockIdx.y * 128;

    const int n = n0 + wave * 16 + cg;
    bf16x8 wf[8];
    #pragma unroll
    for (int chunk = 0; chunk < 8; chunk++)
        wf[chunk] = ld8f_bf(W + (size_t)n * 256 + chunk * 32 + quad * 8);
    const float bv = bias[n];

    #pragma unroll
    for (int l = 0; l < 2; l++) {
        const int m0l = mg + l * 64;
        const unsigned short* Ab = A + (size_t)m0l * 256;

        f32x4 acc[4];
        #pragma unroll
        for (int mi = 0; mi < 4; mi++) acc[mi] = (f32x4){0.f, 0.f, 0.f, 0.f};

        #pragma unroll
        for (int chunk = 0; chunk < 8; chunk++) {
            #pragma unroll
            for (int mi = 0; mi < 4; mi++) {
                bf16x8 af = *(const bf16x8*)(Ab + (size_t)(mi * 16 + cg) * 256 + chunk * 32 + quad * 8);
                acc[mi] = __builtin_amdgcn_mfma_f32_16x16x32_bf16(af, wf[chunk], acc[mi], 0, 0, 0);
            }
        }

        #pragma unroll
        for (int mi = 0; mi < 4; mi++)
            #pragma unroll
            for (int rr = 0; rr < 4; rr++) {
                int m = m0l + mi * 16 + quad * 4 + rr;
                outf[(size_t)m * 256 + n] = acc[mi][rr] + bv;
            }
    }
}

// ---------------------------------------------------------------------------
// Key-split MFMA flash attention (r13 proven version, 48.2 us).
// ---------------------------------------------------------------------------
__global__ __launch_bounds__(256) void attn_mfma_kernel(
    const unsigned short* __restrict__ Q,
    const unsigned short* __restrict__ K,
    const unsigned short* __restrict__ Vt,
    const float* __restrict__ table,
    unsigned short* __restrict__ AO)
{
    __shared__ __align__(16) unsigned short PL[4][64][72];   // 36 KB
    __shared__ __align__(16) unsigned short KA7[7][40];      // 560 B bias rows

    const int t    = threadIdx.x;
    const int wave = t >> 6;
    const int lane = t & 63;
    const int cg   = lane & 15;
    const int quad = lane >> 4;

    const int bid = blockIdx.x;
    const int qt  = bid & 31;
    const int bh  = bid >> 5;
    const int b   = bh >> 3;
    const int h   = bh & 7;
    const int q0  = qt * 64;

    if (t < 224) {
        int r = t >> 5, c = t & 31;
        float v = (c < 7) ? table[c - r + 6] * LOG2E : 0.f;
        KA7[r][c] = f2bf(v);
    }
    __syncthreads();

    const unsigned short* Kbase = K  + (size_t)bh * (SEQ * HD);
    const unsigned short* Vbase = Vt + (size_t)bh * (SEQ * HD);

    bf16x8 qf[4], qfa[4];
    #pragma unroll
    for (int qi = 0; qi < 4; qi++) {
        qf[qi]  = *(const bf16x8*)(Q + (size_t)bh * (SEQ * HD) +
                                   (size_t)(q0 + qi * 16 + cg) * HD + quad * 8);
        int p = (q0 + qi * 16 + cg) % 7;
        #pragma unroll
        for (int i = 0; i < 8; i++)
            qfa[qi][i] = (quad == 0 && i == p) ? (short)0x3F80 : (short)0;
    }

    bf16x8 ones;
    #pragma unroll
    for (int i = 0; i < 8; i++) ones[i] = (short)0x3F80;

    f32x4 o[4][2], ol[4];
    #pragma unroll
    for (int qi = 0; qi < 4; qi++) {
        o[qi][0] = (f32x4){0.f, 0.f, 0.f, 0.f};
        o[qi][1] = (f32x4){0.f, 0.f, 0.f, 0.f};
        ol[qi]   = (f32x4){0.f, 0.f, 0.f, 0.f};
    }

    const int kstart = wave * (SEQ / 4);
    int kb7[4];
    #pragma unroll
    for (int jt = 0; jt < 4; jt++) kb7[jt] = (kstart + jt * 16 + cg) % 7;

    #pragma unroll 2
    for (int jj = 0; jj < SEQ / 4; jj += 64) {
        const int j0 = kstart + jj;

        bf16x8 kf[4], kfa[4];
        #pragma unroll
        for (int jt = 0; jt < 4; jt++) {
            kf[jt]  = *(const bf16x8*)(Kbase + (size_t)(j0 + jt * 16 + cg) * HD + quad * 8);
            kfa[jt] = *(const bf16x8*)&KA7[kb7[jt]][quad * 8];
        }
        bf16x8 vf[2][2];
        #pragma unroll
        for (int kt = 0; kt < 2; kt++)
            #pragma unroll
            for (int dt = 0; dt < 2; dt++)
                vf[kt][dt] = *(const bf16x8*)(Vbase + (size_t)(dt * 16 + cg) * SEQ +
                                              j0 + kt * 32 + quad * 8);

        #pragma unroll
        for (int half = 0; half < 2; half++) {
            f32x4 s[2][4];
            #pragma unroll
            for (int qh = 0; qh < 2; qh++) {
                int qi = half * 2 + qh;
                #pragma unroll
                for (int jt = 0; jt < 4; jt++) {
                    s[qh][jt] = __builtin_amdgcn_mfma_f32_16x16x32_bf16(
                        kfa[jt], qfa[qi], (f32x4){0.f, 0.f, 0.f, 0.f}, 0, 0, 0);
                    s[qh][jt] = __builtin_amdgcn_mfma_f32_16x16x32_bf16(
                        kf[jt], qf[qi], s[qh][jt], 0, 0, 0);
                }
            }
            #pragma unroll
            for (int qh = 0; qh < 2; qh++) {
                int qi = half * 2 + qh;
                #pragma unroll
                for (int jt = 0; jt < 4; jt++) {
                    float p0 = EXP2F(s[qh][jt][0]);
                    float p1 = EXP2F(s[qh][jt][1]);
                    float p2 = EXP2F(s[qh][jt][2]);
                    float p3 = EXP2F(s[qh][jt][3]);
                    uint2 w;
                    w.x = cvt2(p0, p1);
                    w.y = cvt2(p2, p3);
                    *(uint2*)&PL[wave][qi * 16 + cg][jt * 16 + quad * 4] = w;
                }
            }
        }
        __builtin_amdgcn_s_waitcnt(0xC07F);

        #pragma unroll
        for (int qi = 0; qi < 4; qi++) {
            bf16x8 pa0 = *(const bf16x8*)&PL[wave][qi * 16 + cg][quad * 8];
            bf16x8 pa1 = *(const bf16x8*)&PL[wave][qi * 16 + cg][32 + quad * 8];
            o[qi][0] = __builtin_amdgcn_mfma_f32_16x16x32_bf16(pa0, vf[0][0], o[qi][0], 0, 0, 0);
            o[qi][0] = __builtin_amdgcn_mfma_f32_16x16x32_bf16(pa1, vf[1][0], o[qi][0], 0, 0, 0);
            o[qi][1] = __builtin_amdgcn_mfma_f32_16x16x32_bf16(pa0, vf[0][1], o[qi][1], 0, 0, 0);
            o[qi][1] = __builtin_amdgcn_mfma_f32_16x16x32_bf16(pa1, vf[1][1], o[qi][1], 0, 0, 0);
            ol[qi]   = __builtin_amdgcn_mfma_f32_16x16x32_bf16(pa0, ones, ol[qi], 0, 0, 0);
            ol[qi]   = __builtin_amdgcn_mfma_f32_16x16x32_bf16(pa1, ones, ol[qi], 0, 0, 0);
        }

        #pragma unroll
        for (int jt = 0; jt < 4; jt++)
            kb7[jt] = (kb7[jt] == 6) ? 0 : kb7[jt] + 1;
    }

    __builtin_amdgcn_s_waitcnt(0xC07F);
    float* OPw = (float*)&PL[wave][0][0];
    #pragma unroll
    for (int qi = 0; qi < 4; qi++) {
        #pragma unroll
        for (int dt = 0; dt < 2; dt++)
            #pragma unroll
            for (int rr = 0; rr < 4; rr++)
                OPw[(qi * 16 + quad * 4 + rr) * 33 + dt * 16 + cg] = o[qi][dt][rr];
        if (cg == 0) {
            #pragma unroll
            for (int rr = 0; rr < 4; rr++)
                OPw[(qi * 16 + quad * 4 + rr) * 33 + 32] = ol[qi][rr];
        }
    }
    __syncthreads();

    {
        int q  = t >> 2;
        int d0 = (t & 3) << 3;
        float l = 0.f;
        float ov[8];
        #pragma unroll
        for (int i = 0; i < 8; i++) ov[i] = 0.f;
        #pragma unroll
        for (int w = 0; w < 4; w++) {
            const float* OPx = (const float*)&PL[w][0][0];
            l += OPx[q * 33 + 32];
            #pragma unroll
            for (int i = 0; i < 8; i++) ov[i] += OPx[q * 33 + d0 + i];
        }
        float inv = 1.f / l;
        unsigned short pk[8];
        #pragma unroll
        for (int i = 0; i < 8; i += 2) {
            unsigned int u = cvt2(ov[i] * inv, ov[i + 1] * inv);
            pk[i]     = (unsigned short)(u & 0xffffu);
            pk[i + 1] = (unsigned short)(u >> 16);
        }
        *(uint4*)(AO + ((size_t)(b * SEQ + q0 + q)) * DIMC + h * HD + d0) = *(const uint4*)pk;
    }
}

// ---------------------------------------------------------------------------
extern "C" void kernel_launch(void* const* d_in, const int* in_sizes, int n_in,
                              void* d_out, int out_size, void* d_ws, size_t ws_size,
                              hipStream_t stream) {
    const float* x      = (const float*)d_in[0]; // (4,2048,256)
    const float* qkv_w  = (const float*)d_in[1]; // (768,256)
    const float* qkv_b  = (const float*)d_in[2]; // (768)
    const float* proj_w = (const float*)d_in[3]; // (256,256)
    const float* proj_b = (const float*)d_in[4]; // (256)
    const float* table  = (const float*)d_in[5]; // (104)
    float* out = (float*)d_out;                  // (4,2048,256) fp32

    unsigned short* ws   = (unsigned short*)d_ws;
    unsigned short* qb   = ws;                         // [bh][seq][32] bf16 (pre-scaled)
    unsigned short* kb   = qb  + (size_t)QKVN;
    unsigned short* vtb  = kb  + (size_t)QKVN;         // [bh][32][seq]
    unsigned short* ao   = vtb + (size_t)QKVN;         // [B*seq][256]

    // 1) QKV GEMM (barrier-free, register-resident W slices)
    gemm_qkv_kernel<<<dim3(12, 64), 256, 0, stream>>>(
        x, qkv_w, qkv_b, qb, kb, vtb);

    // 2) key-split MFMA flash attention (r13 proven kernel)
    attn_mfma_kernel<<<dim3(BATCH * NHEADS * (SEQ / 64)), 256, 0, stream>>>(
        qb, kb, vtb, table, ao);

    // 3) output projection (barrier-free)
    gemm_proj_kernel<<<dim3(4, 64), 256, 0, stream>>>(
        ao, proj_w, proj_b, out);
}